// Round 3
// baseline (326.824 us; speedup 1.0000x reference)
//
#include <hip/hip_runtime.h>
#include <cstdint>
#include <cstddef>

typedef __bf16 bf16_t;
typedef __bf16 bf16x8 __attribute__((ext_vector_type(8)));
typedef float f32x4 __attribute__((ext_vector_type(4)));

#define MFMA16(a, b, c) __builtin_amdgcn_mfma_f32_16x16x32_bf16((a), (b), (c), 0, 0, 0)

// ---------------- f32 -> bf16 conversion (RNE), vectorized ----------------
__global__ __launch_bounds__(256) void cvt_f32_bf16(const float* __restrict__ src,
                                                    bf16_t* __restrict__ dst, int n4) {
  int stride = gridDim.x * blockDim.x;
  for (int i = blockIdx.x * blockDim.x + threadIdx.x; i < n4; i += stride) {
    float4 v = *(const float4*)(src + (size_t)i * 4);
    ushort4 o;
    o.x = __builtin_bit_cast(unsigned short, (bf16_t)v.x);
    o.y = __builtin_bit_cast(unsigned short, (bf16_t)v.y);
    o.z = __builtin_bit_cast(unsigned short, (bf16_t)v.z);
    o.w = __builtin_bit_cast(unsigned short, (bf16_t)v.w);
    *(ushort4*)(dst + (size_t)i * 4) = o;
  }
}

// ---------------- shared helpers ----------------
__device__ __forceinline__ void gload_lds16(const bf16_t* g, bf16_t* lds) {
  __builtin_amdgcn_global_load_lds(
      (const __attribute__((address_space(1))) unsigned int*)g,
      (__attribute__((address_space(3))) unsigned int*)lds, 16, 0, 0);
}

// tile pitch = 128 B per row; 16B granules XOR-swizzled by (row&7)
__device__ __forceinline__ bf16x8 lds_frag(const bf16_t* tile, int row, int g) {
  int byte = row * 128 + ((g ^ (row & 7)) << 4);
  return *(const bf16x8*)((const char*)tile + byte);
}

__device__ __forceinline__ unsigned cvt_pk_bf16(float lo, float hi) {
  unsigned r;
  asm("v_cvt_pk_bf16_f32 %0, %1, %2" : "=v"(r) : "v"(lo), "v"(hi));
  return r;
}

// ---------------- GEMM: C[M,N] = A[M,K] * B[N,K]^T, bf16 in, f32 acc ------
template <int EPI>
__global__ __launch_bounds__(256)
void gemm_bt(const bf16_t* __restrict__ A, const bf16_t* __restrict__ Bm,
             bf16_t* __restrict__ Qo, bf16_t* __restrict__ Ko,
             bf16_t* __restrict__ Vto, float* __restrict__ Co) {
  const int K = 1024;
  __shared__ bf16_t As[128 * 64];
  __shared__ bf16_t Bs[128 * 64];
  const int wave = threadIdx.x >> 6, lane = threadIdx.x & 63;
  const int lm = lane & 15, lg = lane >> 4;
  const int wm = wave >> 1, wn = wave & 1;
  const int tm = blockIdx.y * 128, tn = blockIdx.x * 128;

  f32x4 zero = {0.f, 0.f, 0.f, 0.f};
  f32x4 acc[4][4];
#pragma unroll
  for (int i = 0; i < 4; ++i)
#pragma unroll
    for (int j = 0; j < 4; ++j) acc[i][j] = zero;

  const int srow = lane >> 3;
  const int gs = lane & 7;

  for (int k0 = 0; k0 < K; k0 += 64) {
#pragma unroll
    for (int c = 0; c < 4; ++c) {
      int cc = wave * 4 + c;
      int row = cc * 8 + srow;
      int gsrc = gs ^ (row & 7);
      gload_lds16(A + (size_t)(tm + row) * K + k0 + gsrc * 8, &As[cc * 512]);
      gload_lds16(Bm + (size_t)(tn + row) * K + k0 + gsrc * 8, &Bs[cc * 512]);
    }
    __syncthreads();
#pragma unroll
    for (int kk = 0; kk < 2; ++kk) {
      bf16x8 af[4], bfr[4];
#pragma unroll
      for (int i = 0; i < 4; ++i) af[i] = lds_frag(As, wm * 64 + i * 16 + lm, kk * 4 + lg);
#pragma unroll
      for (int i = 0; i < 4; ++i) bfr[i] = lds_frag(Bs, wn * 64 + i * 16 + lm, kk * 4 + lg);
#pragma unroll
      for (int mi = 0; mi < 4; ++mi)
#pragma unroll
        for (int ni = 0; ni < 4; ++ni)
          acc[mi][ni] = MFMA16(af[mi], bfr[ni], acc[mi][ni]);
    }
    __syncthreads();
  }

#pragma unroll
  for (int mi = 0; mi < 4; ++mi) {
#pragma unroll
    for (int ni = 0; ni < 4; ++ni) {
#pragma unroll
      for (int r = 0; r < 4; ++r) {
        int m = tm + wm * 64 + mi * 16 + lg * 4 + r;
        int n = tn + wn * 64 + ni * 16 + lm;
        float v = acc[mi][ni][r];
        if (EPI == 0) {
          int which = n >> 10, rem = n & 1023;
          int hh = rem >> 6, d = rem & 63;
          int bb = m >> 11, s = m & 2047;
          size_t bh = (size_t)bb * 16 + hh;
          if (which == 0) {
            // fold softmax scale log2(e)/sqrt(64) into Q
            Qo[(bh * 2048 + s) * 64 + d] = (bf16_t)(v * 0.18033688011112042f);
          } else if (which == 1) {
            Ko[(bh * 2048 + s) * 64 + d] = (bf16_t)v;
          } else {
            Vto[(bh * 64 + d) * 2048 + s] = (bf16_t)v;
          }
        } else {
          Co[(size_t)m * 1024 + n] = v;
        }
      }
    }
  }
}

// ---------------- causal flash attention, swapped-QK^T layout ------------
// Each lane owns ONE q-row (q = qrow0 + (lane&15)); kv is lane-local.
// m/l scalars per lane; P packed via cvt_pk + ds_write_b64; PV computes
// O^T = mfma(A=V^T, B=P) so rescale stays lane-local.
__device__ __forceinline__ void sm_step(const f32x4& s0, const f32x4& s1,
                                        float& m_run, float& l_run, f32x4* acc,
                                        bf16_t* P, int gbase, bool diag,
                                        int lm, int lg, int qrel) {
  float tv[2][4];
#pragma unroll
  for (int nt = 0; nt < 2; ++nt)
#pragma unroll
    for (int r = 0; r < 4; ++r) {
      float v = nt ? s1[r] : s0[r];
      if (diag && (nt * 16 + lg * 4 + r > qrel)) v = -3.0e38f;
      tv[nt][r] = v;
    }
  float mt = fmaxf(fmaxf(fmaxf(tv[0][0], tv[0][1]), fmaxf(tv[0][2], tv[0][3])),
                   fmaxf(fmaxf(tv[1][0], tv[1][1]), fmaxf(tv[1][2], tv[1][3])));
  mt = fmaxf(mt, __shfl_xor(mt, 16));
  mt = fmaxf(mt, __shfl_xor(mt, 32));
  if (!__all(mt <= m_run + 8.f)) {  // defer-max: skip rescale on small growth
    float mn = fmaxf(m_run, mt);
    float scf = __builtin_amdgcn_exp2f(m_run - mn);
    m_run = mn;
    l_run *= scf;
#pragma unroll
    for (int nd = 0; nd < 4; ++nd)
#pragma unroll
      for (int r = 0; r < 4; ++r) acc[nd][r] *= scf;
  }
  float rs = 0.f;
#pragma unroll
  for (int nt = 0; nt < 2; ++nt) {
    float p0 = __builtin_amdgcn_exp2f(tv[nt][0] - m_run);
    float p1 = __builtin_amdgcn_exp2f(tv[nt][1] - m_run);
    float p2 = __builtin_amdgcn_exp2f(tv[nt][2] - m_run);
    float p3 = __builtin_amdgcn_exp2f(tv[nt][3] - m_run);
    rs += (p0 + p1) + (p2 + p3);
    uint2 pw;
    pw.x = cvt_pk_bf16(p0, p1);
    pw.y = cvt_pk_bf16(p2, p3);
    int gr = (gbase + nt * 2 + (lg >> 1)) ^ (lm & 7);
    *(uint2*)((char*)P + lm * 128 + gr * 16 + (lg & 1) * 8) = pw;
  }
  rs += __shfl_xor(rs, 16);
  rs += __shfl_xor(rs, 32);
  l_run += rs;
}

__device__ __forceinline__ void pv_step(const bf16_t* P, int gbase, const bf16x8 bv[4],
                                        f32x4* acc, int lm, int lg) {
  int gr = (gbase + lg) ^ (lm & 7);
  bf16x8 pf = *(const bf16x8*)((const char*)P + lm * 128 + gr * 16);
#pragma unroll
  for (int nd = 0; nd < 4; ++nd) acc[nd] = MFMA16(bv[nd], pf, acc[nd]);
}

__global__ __launch_bounds__(256, 4)
void attn_fwd(const bf16_t* __restrict__ Q, const bf16_t* __restrict__ K,
              const bf16_t* __restrict__ Vt, bf16_t* __restrict__ Aout) {
  const int S = 2048;
  const int i = blockIdx.x;
  // XCD-locality decode: all 16 pair-blocks of one bh land on the same XCD
  const int bh = (i & 7) * 8 + ((i >> 3) & 7);
  const int p = i >> 6;            // pair 0..15
  const int hL = p, hH = 31 - p;   // paired 64-row q-tiles (balanced work)
  const int b = bh >> 4, h = bh & 15;
  const int w = threadIdx.x >> 6, lane = threadIdx.x & 63;
  const int lm = lane & 15, lg = lane >> 4;
  const int qrowL = hL * 64 + w * 16;
  const int qrowH = hH * 64 + w * 16;
  const int qrel = ((w & 1) << 4) + lm;  // q - kv0 at the diagonal step

  const bf16_t* Qb = Q + (size_t)bh * S * 64;
  const bf16_t* Kb = K + (size_t)bh * S * 64;
  const bf16_t* Vb = Vt + (size_t)bh * 64 * S;

  __shared__ bf16_t Plds[4][16 * 64];  // per-wave; L = granules 0-3, H = 4-7
  bf16_t* P = Plds[w];

  bf16x8 aqL[2], aqH[2];
#pragma unroll
  for (int kk = 0; kk < 2; ++kk) {
    aqL[kk] = *(const bf16x8*)(Qb + (size_t)(qrowL + lm) * 64 + kk * 32 + lg * 8);
    aqH[kk] = *(const bf16x8*)(Qb + (size_t)(qrowH + lm) * 64 + kk * 32 + lg * 8);
  }

  float mL = -3.0e38f, lL = 0.f, mH = -3.0e38f, lH = 0.f;
  f32x4 zero = {0.f, 0.f, 0.f, 0.f};
  f32x4 accL[4], accH[4];
#pragma unroll
  for (int nd = 0; nd < 4; ++nd) { accL[nd] = zero; accH[nd] = zero; }

  const int sLend = hL * 2 + (w >> 1);  // inclusive diagonal kv-step (32 wide)
  const int sHend = hH * 2 + (w >> 1);

  for (int s = 0; s <= sHend; ++s) {
    const int kv0 = s * 32;
    bf16x8 bk[2][2], bv[4];
#pragma unroll
    for (int nt = 0; nt < 2; ++nt)
#pragma unroll
      for (int kk = 0; kk < 2; ++kk)
        bk[nt][kk] = *(const bf16x8*)(Kb + (size_t)(kv0 + nt * 16 + lm) * 64 + kk * 32 + lg * 8);
#pragma unroll
    for (int nd = 0; nd < 4; ++nd)
      bv[nd] = *(const bf16x8*)(Vb + (size_t)(nd * 16 + lm) * S + kv0 + lg * 8);

    // QK^T transposed: C[kv][q], lane holds kv = nt*16+lg*4+r for q = lm
    f32x4 sh0 = MFMA16(bk[0][0], aqH[0], zero);
    sh0 = MFMA16(bk[0][1], aqH[1], sh0);
    f32x4 sh1 = MFMA16(bk[1][0], aqH[0], zero);
    sh1 = MFMA16(bk[1][1], aqH[1], sh1);
    const bool actL = (s <= sLend);
    f32x4 sl0, sl1;
    if (actL) {
      sl0 = MFMA16(bk[0][0], aqL[0], zero);
      sl0 = MFMA16(bk[0][1], aqL[1], sl0);
      sl1 = MFMA16(bk[1][0], aqL[0], zero);
      sl1 = MFMA16(bk[1][1], aqL[1], sl1);
    }
    sm_step(sh0, sh1, mH, lH, accH, P, 4, s == sHend, lm, lg, qrel);
    if (actL) sm_step(sl0, sl1, mL, lL, accL, P, 0, s == sLend, lm, lg, qrel);
    pv_step(P, 4, bv, accH, lm, lg);
    if (actL) pv_step(P, 0, bv, accL, lm, lg);
  }

  const float rlH = 1.f / lH, rlL = 1.f / lL;
#pragma unroll
  for (int nd = 0; nd < 4; ++nd) {
    uint2 oH, oL;
    oH.x = cvt_pk_bf16(accH[nd][0] * rlH, accH[nd][1] * rlH);
    oH.y = cvt_pk_bf16(accH[nd][2] * rlH, accH[nd][3] * rlH);
    oL.x = cvt_pk_bf16(accL[nd][0] * rlL, accL[nd][1] * rlL);
    oL.y = cvt_pk_bf16(accL[nd][2] * rlL, accL[nd][3] * rlL);
    size_t col = (size_t)(h * 64 + nd * 16 + lg * 4);
    *(uint2*)(Aout + ((size_t)(b * 2048 + qrowH + lm)) * 1024 + col) = oH;
    *(uint2*)(Aout + ((size_t)(b * 2048 + qrowL + lm)) * 1024 + col) = oL;
  }
}

// ---------------- launch -----------------
extern "C" void kernel_launch(void* const* d_in, const int* in_sizes, int n_in,
                              void* d_out, int out_size, void* d_ws, size_t ws_size,
                              hipStream_t stream) {
  (void)in_sizes; (void)n_in; (void)out_size; (void)ws_size;
  const float* x  = (const float*)d_in[0];
  const float* Wq = (const float*)d_in[1];
  const float* Wk = (const float*)d_in[2];
  const float* Wv = (const float*)d_in[3];
  const float* Wo = (const float*)d_in[4];

  char* w = (char*)d_ws;
  bf16_t* xb    = (bf16_t*)(w);                 // 8192x1024      (16 MiB)
  bf16_t* wb    = (bf16_t*)(w + 16777216);      // 3072x1024      (6 MiB)
  bf16_t* wob   = (bf16_t*)(w + 23068672);      // 1024x1024      (2 MiB)
  bf16_t* qb    = (bf16_t*)(w + 25165824);      // [B,H,S,64]     (16 MiB)
  bf16_t* kb    = (bf16_t*)(w + 41943040);      // [B,H,S,64]     (16 MiB)
  bf16_t* vtb   = (bf16_t*)(w + 58720256);      // [B,H,64,S]     (16 MiB)
  bf16_t* attnb = (bf16_t*)(w + 75497472);      // [B,S,1024]     (16 MiB)

  cvt_f32_bf16<<<512, 256, 0, stream>>>(x, xb, 8388608 / 4);
  cvt_f32_bf16<<<256, 256, 0, stream>>>(Wq, wb, 1048576 / 4);
  cvt_f32_bf16<<<256, 256, 0, stream>>>(Wk, wb + 1048576, 1048576 / 4);
  cvt_f32_bf16<<<256, 256, 0, stream>>>(Wv, wb + 2097152, 1048576 / 4);
  cvt_f32_bf16<<<256, 256, 0, stream>>>(Wo, wob, 1048576 / 4);

  // QKV projection: M=8192, N=3072, K=1024
  gemm_bt<0><<<dim3(24, 64), 256, 0, stream>>>(xb, wb, qb, kb, vtb, nullptr);
  // causal attention (paired q-tiles, swapped softmax)
  attn_fwd<<<dim3(1024), 256, 0, stream>>>(qb, kb, vtb, attnb);
  // output projection: M=8192, N=1024, K=1024
  gemm_bt<1><<<dim3(8, 64), 256, 0, stream>>>(attnb, wob, nullptr, nullptr, nullptr,
                                              (float*)d_out);
}